// Round 9
// baseline (390.690 us; speedup 1.0000x reference)
//
#include <hip/hip_runtime.h>
#include <hip/hip_bf16.h>

// PINN fused forward+jvp^2 via split-fp16 MFMA.
// R18 = R17 residency (BS=16, 512thr, 2 blocks/CU, 66.6KB LDS, staged A,
// setprio, MFMA tail) with the MFMA shape upgraded to 32x32x16 and the
// 32-column dim packed as [16 samples x 2 channels]:
//   B1 = [vhi|vlo] (planes contiguous at 16*STR -> uniform addressing),
//   B2 = [dhi|ddh].
//   Per (32-row tile, K=16) only 3 MFMAs:
//     accVa += Whi*B1 ; accVb += Wlo*B1  (col s + col s+16 = FULL 4-term
//       split product, more accurate than R17's 3-term)
//     accD  += Whi*B2  (cols<16 = d, cols>=16 = dd in ONE instruction)
//   Epilogue: shfl_xor(16) combines halves; v-half lanes (col<16) write
//   vhi/vlo, d-half lanes write dhi/ddh.
// Instruction count 2729 -> 1604 MFMAs/block (-41% issue slots, equal
// matrix-pipe cycles) -- attacks the issue-port saturation R17 exposed
// (MfmaUtil 35 + VALUBusy 42 = 77% issue).
// C-layout (m74/m101): col=lane&31, row=(reg&3)+8*(reg>>2)+4*(lane>>5).
// A/B: row/col=lane&31, k=(lane>>5)*8+e (extension of this kernel's
// verified 16x16 mapping).

#define NSAMP 65536
#define Q     100
#define DTC   0.8f
#define BS    16
#define THREADS 512
#define STR   520          // LDS plane row stride (halves); mult of 8

typedef _Float16 h8 __attribute__((ext_vector_type(8)));
typedef _Float16 h4 __attribute__((ext_vector_type(4)));
typedef float    f4 __attribute__((ext_vector_type(4)));
typedef float    fv16 __attribute__((ext_vector_type(16)));

// ---- packed fragment-ready weight geometry (halves) ----
// frag = 64 lanes x 8 halves = 512 halves = 32 rows x 16 k
// L1: MT=2,  KT=2  ->   2048   (K=20->32,  FOUT=50->64)
// L2: MT=7,  KT=4  ->  14336   (K=50->64,  FOUT=200->224)
// L3: MT=16, KT=13 -> 106496   (K=200->208,FOUT=500->512)
// L4: MT=7,  KT=32 -> 114688   (K=500->512,FOUT=200->224)
// L5: MT=4,  KT=13 ->  26624   (K=200->208,FOUT=100->128)
// L6: MT=4,  KT=7  ->  14336   (Aext=[A;bvec;0] 112x100->128x112)
#define SW 278528
#define C1 0
#define C2 2048
#define C3 16384
#define C4 122880
#define C5 237568
#define C6 264192
#define BP1 0
#define BP2 64
#define BP3 288
#define BP4 800
#define BP5 1024
#define BPTOT 1152
#define WS_BIAS_BYTE_OFF (SW*2*2)

__device__ __forceinline__ float fast_tanh(float z) {
    float az = fabsf(z);
    float e  = __expf(-2.0f * az);
    float r  = __builtin_amdgcn_rcpf(1.0f + e);
    float t  = (1.0f - e) * r;
    return copysignf(t, z);
}

struct Split { _Float16 hi, lo; };
__device__ __forceinline__ Split split16(float v) {
    Split s;
    s.hi = (_Float16)v;
    s.lo = (_Float16)(v - (float)s.hi);
    return s;
}

__device__ __forceinline__ fv16 zero16() {
    fv16 z;
#pragma unroll
    for (int r = 0; r < 16; ++r) z[r] = 0.f;
    return z;
}

// ---------------- pre-pass: split/pad/PACK weights + biases + Aext ----------------
// frag layout: lane l, elem e -> row = l&31, k = (l>>5)*8 + e
__global__ __launch_bounds__(256) void prepass(
    const float* __restrict__ W1, const float* __restrict__ b1,
    const float* __restrict__ W2, const float* __restrict__ b2,
    const float* __restrict__ W3, const float* __restrict__ b3,
    const float* __restrict__ W4, const float* __restrict__ b4,
    const float* __restrict__ W5, const float* __restrict__ b5,
    const float* __restrict__ Amat, const float* __restrict__ bvec,
    _Float16* __restrict__ whi, float* __restrict__ biasP)
{
    int idx = blockIdx.x * 256 + threadIdx.x;
    _Float16* wlo = whi + SW;
    if (idx < SW) {
        int base, KT, K, FOUT; const float* W; bool ext = false;
        if      (idx < C2) { base=C1; KT=2;  K=20;  FOUT=50;  W=W1; }
        else if (idx < C3) { base=C2; KT=4;  K=50;  FOUT=200; W=W2; }
        else if (idx < C4) { base=C3; KT=13; K=200; FOUT=500; W=W3; }
        else if (idx < C5) { base=C4; KT=32; K=500; FOUT=200; W=W4; }
        else if (idx < C6) { base=C5; KT=13; K=200; FOUT=100; W=W5; }
        else               { base=C6; KT=7;  K=100; FOUT=101; W=Amat; ext = true; }
        int r    = idx - base;
        int frag = r >> 9;
        int f    = r & 511;
        int lane = f >> 3;
        int e    = f & 7;
        int row  = lane & 31;
        int kg   = lane >> 5;
        int mt   = frag / KT;
        int kt   = frag - mt * KT;
        int o = mt * 32 + row;
        int k = kt * 16 + kg * 8 + e;
        float v = 0.f;
        if (o < FOUT && k < K) {
            if (ext && o == 100) v = bvec[k];
            else                 v = W[o * K + k];
        }
        Split sp = split16(v);
        whi[idx] = sp.hi; wlo[idx] = sp.lo;
    } else if (idx < SW + BPTOT) {
        int b = idx - SW;
        const float* src; int FOUT; int o;
        if      (b < BP2)  { src=b1; FOUT=50;  o=b;        }
        else if (b < BP3)  { src=b2; FOUT=200; o=b-BP2;    }
        else if (b < BP4)  { src=b3; FOUT=500; o=b-BP3;    }
        else if (b < BP5)  { src=b4; FOUT=200; o=b-BP4;    }
        else               { src=b5; FOUT=100; o=b-BP5;    }
        biasP[b] = (o < FOUT) ? src[o] : 0.f;
    }
}

// ---------------- one 32x32x16 packed-column MFMA layer ----------------
// smem layout: [vhi 16xSTR][vlo][dhi][ddh] contiguous.
// B1 addr = smem + (lane&31)*STR + (lane>>5)*8 + kt*16 (cols>=16 land in vlo)
// B2 addr = same from smem + 32*STR (spans dhi|ddh).
// A-frag: packed, wcoff + (mt*KT+kt)*512 + lane*8 -> coalesced 1KB load.
// 3 MFMAs per (tile,kt). Epilogue: shfl_xor(16) combines column halves;
// v-half lanes (lane&16==0) write vhi/vlo, d-half lanes write dhi/ddh.
template<int KT, int MTILES, int NMT, int NWACT, int FOUT>
__device__ __forceinline__ void layer32(
    const _Float16* __restrict__ whi, const _Float16* __restrict__ wlo,
    int wcoff, const float* __restrict__ biasP,
    _Float16* smem, int lane, int wv)
{
    constexpr bool STG = (NMT == 1);
    static_assert(MTILES == NMT * NWACT, "exact tiling expected");
    _Float16* B1p = smem;
    _Float16* B2p = smem + 32 * STR;
    const bool act = (wv < NWACT);

    fv16 accVa[NMT], accVb[STG ? 1 : NMT], accD[NMT];

    if (act) {
#pragma unroll
        for (int i = 0; i < NMT; ++i) { accVa[i] = zero16(); accD[i] = zero16(); }
        if constexpr (STG) accVb[0] = zero16();

        const int boff = (lane & 31) * STR + (lane >> 5) * 8;

        if constexpr (STG) {
            const unsigned aoff = (unsigned)(wcoff + (wv * KT) * 512 + lane * 8);
            h8 Ah = *(const h8*)(whi + aoff);
            h8 Al = *(const h8*)(wlo + aoff);
            h8 Ah2, Al2;
#pragma unroll 2
            for (int kt = 0; kt < KT; ++kt) {
                if (kt + 1 < KT) {
                    Ah2 = *(const h8*)(whi + aoff + (kt + 1) * 512);
                    Al2 = *(const h8*)(wlo + aoff + (kt + 1) * 512);
                }
                h8 B1 = *(const h8*)(B1p + boff + kt * 16);
                h8 B2 = *(const h8*)(B2p + boff + kt * 16);
                __builtin_amdgcn_s_setprio(1);
                accVa[0] = __builtin_amdgcn_mfma_f32_32x32x16_f16(Ah, B1, accVa[0], 0, 0, 0);
                accVb[0] = __builtin_amdgcn_mfma_f32_32x32x16_f16(Al, B1, accVb[0], 0, 0, 0);
                accD[0]  = __builtin_amdgcn_mfma_f32_32x32x16_f16(Ah, B2, accD[0],  0, 0, 0);
                __builtin_amdgcn_s_setprio(0);
                if (kt + 1 < KT) { Ah = Ah2; Al = Al2; }
            }
        } else {
            unsigned woff[NMT];
#pragma unroll
            for (int i = 0; i < NMT; ++i)
                woff[i] = (unsigned)(wcoff + ((wv + NWACT * i) * KT) * 512 + lane * 8);
#pragma unroll 2
            for (int kt = 0; kt < KT; ++kt) {
                h8 B1 = *(const h8*)(B1p + boff + kt * 16);
                h8 B2 = *(const h8*)(B2p + boff + kt * 16);
                __builtin_amdgcn_s_setprio(1);
#pragma unroll
                for (int i = 0; i < NMT; ++i) {
                    h8 Ahi = *(const h8*)(whi + woff[i] + kt * 512);
                    h8 Alo = *(const h8*)(wlo + woff[i] + kt * 512);
                    accVa[i] = __builtin_amdgcn_mfma_f32_32x32x16_f16(Ahi, B1, accVa[i], 0, 0, 0);
                    accVa[i] = __builtin_amdgcn_mfma_f32_32x32x16_f16(Alo, B1, accVa[i], 0, 0, 0);
                    accD[i]  = __builtin_amdgcn_mfma_f32_32x32x16_f16(Ahi, B2, accD[i],  0, 0, 0);
                }
                __builtin_amdgcn_s_setprio(0);
            }
        }
    }
    __syncthreads();   // all plane reads complete before in-place overwrite

    if (act) {
        const int  s  = lane & 15;
        const bool vH = (lane & 16) == 0;   // col<16 -> v-channel half
        const int  hi = lane >> 5;
#pragma unroll
        for (int i = 0; i < NMT; ++i) {
            int mt = wv + NWACT * i;
#pragma unroll
            for (int q = 0; q < 4; ++q) {
                int o0 = mt * 32 + q * 8 + hi * 4;
                f4 bi = *(const f4*)(biasP + o0);
                h4 pA, pB;
#pragma unroll
                for (int r = 0; r < 4; ++r) {
                    int reg = q * 4 + r;
                    float sv;
                    if constexpr (STG) sv = accVa[0][reg] + accVb[0][reg];
                    else               sv = accVa[i][reg];
                    float zv = sv + __shfl_xor(sv, 16) + bi[r];
                    float dn = accD[i][reg];
                    float dx = __shfl_xor(dn, 16);
                    float zd  = vH ? dn : dx;
                    float zdd = vH ? dx : dn;
                    float t  = fast_tanh(zv);
                    float s2 = 1.0f - t * t;
                    _Float16 a_, b_;
                    if (vH) {
                        Split sp = split16(t);
                        a_ = sp.hi; b_ = sp.lo;
                    } else {
                        float od  = s2 * zd;
                        float odd = s2 * zdd - 2.0f * t * s2 * zd * zd;
                        a_ = (_Float16)od; b_ = (_Float16)odd;
                    }
                    if (o0 + r >= FOUT) { a_ = (_Float16)0.f; b_ = (_Float16)0.f; }
                    pA[r] = a_; pB[r] = b_;
                }
                _Float16* P = (vH ? smem : smem + 32 * STR) + s * STR + o0;
                *(h4*)(P)            = pA;
                *(h4*)(P + 16 * STR) = pB;
            }
        }
    }
    __syncthreads();
}

// ---------------- main fused kernel ----------------
__global__ __launch_bounds__(THREADS, 4) void pinn_mfma(
    const float* __restrict__ W0, const float* __restrict__ b0,
    const float* __restrict__ x,
    const _Float16* __restrict__ whi, const float* __restrict__ biasP,
    float* __restrict__ out)
{
    __shared__ __align__(16) _Float16 smem[64 * STR];   // 66,560 B
    __shared__ float xs[BS];
    __shared__ float cbv[BS];

    _Float16* vhi = smem;
    _Float16* vlo = smem + 16 * STR;
    _Float16* dhi = smem + 32 * STR;
    _Float16* ddh = smem + 48 * STR;

    const int tid  = threadIdx.x;
    const int bid  = blockIdx.x;
    const int lane = tid & 63;
    const int wv   = tid >> 6;
    const _Float16* wlo = whi + SW;

    if (tid < BS) xs[tid] = x[bid * BS + tid];
    __syncthreads();

    // ---- layer 0: 1 -> 20, write padded-K (32) input planes ----
    {
        int s = tid >> 5;       // 0..15
        int k = tid & 31;       // 0..31
        float v0 = 0.f, v1 = 0.f, v2 = 0.f;
        if (k < 20) {
            float w  = W0[k];
            float z  = w * xs[s] + b0[k];
            float t  = fast_tanh(z);
            float s2 = 1.0f - t * t;
            v0 = t; v1 = s2 * w; v2 = -2.0f * t * s2 * w * w;
        }
        Split s0 = split16(v0);
        int off = s * STR + k;
        vhi[off] = s0.hi;           vlo[off] = s0.lo;
        dhi[off] = (_Float16)v1;    ddh[off] = (_Float16)v2;
    }
    __syncthreads();

    //        KT  MT NMT NWA FOUT
    layer32<  2,  2, 1,  2,  50>(whi, wlo, C1, biasP + BP1, smem, lane, wv);
    layer32<  4,  7, 1,  7, 200>(whi, wlo, C2, biasP + BP2, smem, lane, wv);
    layer32< 13, 16, 2,  8, 500>(whi, wlo, C3, biasP + BP3, smem, lane, wv);
    layer32< 32,  7, 1,  7, 200>(whi, wlo, C4, biasP + BP4, smem, lane, wv);

    // ---- layer 5 (200->100 linear) -> U, Uxx, F; F split into vhi/vlo,
    //      U fp32 into dhi; then tail MFMA [A;bvec]@F and store ----
    {
        const int  s  = lane & 15;
        const bool vH = (lane & 16) == 0;
        const int  hi = lane >> 5;
        float* Umf = (float*)(smem + 32 * STR);   // dhi plane as f32 [16][104]

        // -- L5 MFMA (KT=13, 4 tiles, waves 0-3) --
        {
            const bool act = (wv < 4);
            fv16 aa = zero16(), ab = zero16(), ad = zero16();
            if (act) {
                const int boff = (lane & 31) * STR + (lane >> 5) * 8;
                const unsigned aoff = (unsigned)(C5 + (wv * 13) * 512 + lane * 8);
                h8 Ah = *(const h8*)(whi + aoff);
                h8 Al = *(const h8*)(wlo + aoff);
                h8 Ah2, Al2;
#pragma unroll 2
                for (int kt = 0; kt < 13; ++kt) {
                    if (kt + 1 < 13) {
                        Ah2 = *(const h8*)(whi + aoff + (kt + 1) * 512);
                        Al2 = *(const h8*)(wlo + aoff + (kt + 1) * 512);
                    }
                    h8 B1 = *(const h8*)(vhi + boff + kt * 16);
                    h8 B2 = *(const h8*)(dhi + boff + kt * 16);
                    __builtin_amdgcn_s_setprio(1);
                    aa = __builtin_amdgcn_mfma_f32_32x32x16_f16(Ah, B1, aa, 0, 0, 0);
                    ab = __builtin_amdgcn_mfma_f32_32x32x16_f16(Al, B1, ab, 0, 0, 0);
                    ad = __builtin_amdgcn_mfma_f32_32x32x16_f16(Ah, B2, ad, 0, 0, 0);
                    __builtin_amdgcn_s_setprio(0);
                    if (kt + 1 < 13) { Ah = Ah2; Al = Al2; }
                }
            }
            __syncthreads();   // plane reads done; overwrite with F / U

            if (act) {
                float xv = xs[s];
                float xm = xv * xv - 1.0f;
#pragma unroll
                for (int q = 0; q < 4; ++q) {
                    int o0 = wv * 32 + q * 8 + hi * 4;
                    f4 bi = *(const f4*)(biasP + BP5 + o0);
                    h4 pA, pB; f4 uo;
#pragma unroll
                    for (int r = 0; r < 4; ++r) {
                        int reg = q * 4 + r;
                        float sv = aa[reg] + ab[reg];
                        float zv = sv + __shfl_xor(sv, 16) + bi[r];
                        float dn = ad[reg];
                        float dx = __shfl_xor(dn, 16);
                        float zd  = vH ? dn : dx;
                        float zdd = vH ? dx : dn;
                        float U   = -1.0f + xm * zv;
                        float Uxx = 2.0f * zv + 4.0f * xv * zd + xm * zdd;
                        float Fv  = 5.0f * U * U * U - 5.0f * U - 0.0005f * Uxx;
                        if (o0 + r >= Q) Fv = 0.f;
                        Split sp = split16(Fv);
                        pA[r] = sp.hi; pB[r] = sp.lo;
                        uo[r] = U;
                    }
                    if (vH) {
                        _Float16* P = vhi + s * STR + o0;
                        *(h4*)(P)            = pA;
                        *(h4*)(P + 16 * STR) = pB;
                    } else if (o0 <= 96) {
                        *(f4*)(Umf + s * 104 + o0) = uo;
                    }
                }
            }
            __syncthreads();
        }

        // -- tail MFMA: Aext(128x112) @ F -> U0 increments; row 100 = cb --
        {
            const bool act = (wv < 4);
            fv16 ta = zero16(), tb = zero16();
            if (act) {
                const int boff = (lane & 31) * STR + (lane >> 5) * 8;
                const unsigned aoff = (unsigned)(C6 + (wv * 7) * 512 + lane * 8);
                h8 Ah = *(const h8*)(whi + aoff);
                h8 Al = *(const h8*)(wlo + aoff);
                h8 Ah2, Al2;
#pragma unroll 2
                for (int kt = 0; kt < 7; ++kt) {
                    if (kt + 1 < 7) {
                        Ah2 = *(const h8*)(whi + aoff + (kt + 1) * 512);
                        Al2 = *(const h8*)(wlo + aoff + (kt + 1) * 512);
                    }
                    h8 B1 = *(const h8*)(vhi + boff + kt * 16);
                    __builtin_amdgcn_s_setprio(1);
                    ta = __builtin_amdgcn_mfma_f32_32x32x16_f16(Ah, B1, ta, 0, 0, 0);
                    tb = __builtin_amdgcn_mfma_f32_32x32x16_f16(Al, B1, tb, 0, 0, 0);
                    __builtin_amdgcn_s_setprio(0);
                    if (kt + 1 < 7) { Ah = Ah2; Al = Al2; }
                }
            }
            float tot[16];
            if (act) {
#pragma unroll
                for (int reg = 0; reg < 16; ++reg) {
                    float sv = ta[reg] + tb[reg];
                    tot[reg] = sv + __shfl_xor(sv, 16);
                }
                // cb = row 100 of Aext@F: tile 3, local row 4 -> reg 0, hi==1
                if (wv == 3 && hi == 1 && vH) cbv[s] = DTC * tot[0];
            }
            __syncthreads();
            if (act) {
                float cbs = cbv[s];
                int sg = bid * BS + s;
#pragma unroll
                for (int q = 0; q < 4; ++q) {
                    int q0 = wv * 32 + q * 8 + hi * 4;
                    if (q0 <= 96) {
                        f4 um = *(const f4*)(Umf + s * 104 + q0);
                        f4 o4;
#pragma unroll
                        for (int r = 0; r < 4; ++r)
                            o4[r] = um[r] + DTC * tot[q * 4 + r];
                        if (vH) {
                            *(f4*)(out + sg * Q + q0) = o4;
                        } else {
#pragma unroll
                            for (int r = 0; r < 4; ++r) o4[r] -= cbs;
                            *(f4*)(out + NSAMP * Q + sg * Q + q0) = o4;
                        }
                    }
                }
            }
        }
    }
}

extern "C" void kernel_launch(void* const* d_in, const int* in_sizes, int n_in,
                              void* d_out, int out_size, void* d_ws, size_t ws_size,
                              hipStream_t stream) {
    const float* W0 = (const float*)d_in[0];
    const float* b0 = (const float*)d_in[1];
    const float* W1 = (const float*)d_in[2];
    const float* b1 = (const float*)d_in[3];
    const float* W2 = (const float*)d_in[4];
    const float* b2 = (const float*)d_in[5];
    const float* W3 = (const float*)d_in[6];
    const float* b3 = (const float*)d_in[7];
    const float* W4 = (const float*)d_in[8];
    const float* b4 = (const float*)d_in[9];
    const float* W5 = (const float*)d_in[10];
    const float* b5 = (const float*)d_in[11];
    const float* x  = (const float*)d_in[12];
    const float* A  = (const float*)d_in[13];
    const float* bv = (const float*)d_in[14];
    float* out = (float*)d_out;

    _Float16* whi = (_Float16*)d_ws;
    float* biasP  = (float*)((char*)d_ws + WS_BIAS_BYTE_OFF);

    prepass<<<(SW + BPTOT + 255) / 256, 256, 0, stream>>>(
        W1, b1, W2, b2, W3, b3, W4, b4, W5, b5, A, bv, whi, biasP);

    pinn_mfma<<<NSAMP / BS, THREADS, 0, stream>>>(
        W0, b0, x, whi, biasP, out);
}

// Round 10
// 304.847 us; speedup vs baseline: 1.2816x; 1.2816x over previous
//
#include <hip/hip_runtime.h>
#include <hip/hip_bf16.h>

// PINN fused forward+jvp^2 via split-fp16 MFMA.
// R19 = R17 (244us best: BS=16, 512thr, 2 blocks/CU, STR=520, 16x16x32
// split-fp16 5-MFMA layers, staged A-frags, vb-split, setprio, MFMA tail
// via Aext=[A;bvec;0]) + two surgical cuts:
//  (1) FOUT guards in layer epilogues REMOVED: prepass zero-pads weight
//      rows>=FOUT and biases, so out-of-range outputs evaluate to exactly
//      0 anyway (tanh(0)=0, s2*0=0). Saves cmp+3..6 cndmask per element
//      in the largest VALU block. (L5/tail guards kept: memory safety.)
//  (2) kt loops FULLY unrolled (was unroll 2): kills the Ah=Ah2 rotation
//      movs and lets the compiler deepen the load pipeline into the
//      ~20-VGPR headroom (unified 128 - 48 AGPR = 80; using 60).
// R18 lesson: 32x32 shape regressed (-29%) -- fewer/longer dependent MFMA
// chains starve the pipe; many parallel 16x16 chains win at M=16.

#define NSAMP 65536
#define Q     100
#define DTC   0.8f
#define BS    16
#define THREADS 512
#define STR   520          // LDS plane stride (halves); MUST be mult of 8

typedef _Float16 h8 __attribute__((ext_vector_type(8)));
typedef _Float16 h4 __attribute__((ext_vector_type(4)));
typedef float    f4 __attribute__((ext_vector_type(4)));

// ---- packed fragment-ready weight geometry (halves) ----
// per layer: MT * KT * 512 halves (frag = 64 lanes x 8 halves)
// L1: MT=4,  KT=1  ->   2048
// L2: MT=14, KT=2  ->  14336
// L3: MT=32, KT=7  -> 114688
// L4: MT=14, KT=16 -> 114688
// L5: MT=7,  KT=7  ->  25088
// L6 (Aext=[A;bvec;0], 112x100): MT=7, KT=4 -> 14336
#define SW 285184
#define C1 0
#define C2 2048
#define C3 16384
#define C4 131072
#define C5 245760
#define C6 270848
#define BP1 0
#define BP2 64
#define BP3 288
#define BP4 800
#define BP5 1024
#define BPTOT 1136
#define WS_BIAS_BYTE_OFF (SW*2*2)

__device__ __forceinline__ float fast_tanh(float z) {
    float az = fabsf(z);
    float e  = __expf(-2.0f * az);
    float r  = __builtin_amdgcn_rcpf(1.0f + e);
    float t  = (1.0f - e) * r;
    return copysignf(t, z);
}

struct Split { _Float16 hi, lo; };
__device__ __forceinline__ Split split16(float v) {
    Split s;
    s.hi = (_Float16)v;
    s.lo = (_Float16)(v - (float)s.hi);
    return s;
}

// ---------------- pre-pass: split/pad/PACK weights + biases + Aext into d_ws ----------------
__global__ __launch_bounds__(256) void prepass(
    const float* __restrict__ W1, const float* __restrict__ b1,
    const float* __restrict__ W2, const float* __restrict__ b2,
    const float* __restrict__ W3, const float* __restrict__ b3,
    const float* __restrict__ W4, const float* __restrict__ b4,
    const float* __restrict__ W5, const float* __restrict__ b5,
    const float* __restrict__ Amat, const float* __restrict__ bvec,
    _Float16* __restrict__ whi, float* __restrict__ biasP)
{
    int idx = blockIdx.x * 256 + threadIdx.x;
    _Float16* wlo = whi + SW;
    if (idx < SW) {
        int base, KT, K, FOUT; const float* W; bool ext = false;
        if      (idx < C2) { base=C1; KT=1;  K=20;  FOUT=50;  W=W1; }
        else if (idx < C3) { base=C2; KT=2;  K=50;  FOUT=200; W=W2; }
        else if (idx < C4) { base=C3; KT=7;  K=200; FOUT=500; W=W3; }
        else if (idx < C5) { base=C4; KT=16; K=500; FOUT=200; W=W4; }
        else if (idx < C6) { base=C5; KT=7;  K=200; FOUT=100; W=W5; }
        else               { base=C6; KT=4;  K=100; FOUT=101; W=Amat; ext = true; }
        int r    = idx - base;
        int frag = r >> 9;
        int f    = r & 511;
        int lane = f >> 3;
        int e    = f & 7;
        int colS = lane & 15;
        int kg   = lane >> 4;
        int mt   = frag / KT;
        int kt   = frag - mt * KT;
        int o = mt * 16 + colS;
        int k = kt * 32 + kg * 8 + e;
        float v = 0.f;
        if (o < FOUT && k < K) {
            if (ext && o == 100) v = bvec[k];
            else                 v = W[o * K + k];
        }
        Split sp = split16(v);
        whi[idx] = sp.hi; wlo[idx] = sp.lo;
    } else if (idx < SW + BPTOT) {
        int b = idx - SW;
        const float* src; int FOUT; int o;
        if      (b < BP2)  { src=b1; FOUT=50;  o=b;        }
        else if (b < BP3)  { src=b2; FOUT=200; o=b-BP2;    }
        else if (b < BP4)  { src=b3; FOUT=500; o=b-BP3;    }
        else if (b < BP5)  { src=b4; FOUT=200; o=b-BP4;    }
        else               { src=b5; FOUT=100; o=b-BP5;    }
        biasP[b] = (o < FOUT) ? src[o] : 0.f;
    }
}

// ---------------- one MFMA layer ----------------
// Planes (LDS, stride STR halves): vhi, vlo (split v-state), dhi, ddh (fp16 d/dd).
// B-frag: lane l -> col = l&15 (sample), k0 = (l>>4)*8 + kt*32.
// A-frag: PACKED: base + (mt*KT + kt)*512 + lane*8  -> coalesced 1KB load.
// C/D: col(lane&15)=sample, row((lane>>4)*4+reg)=output neuron.
// Staged path (NMT<=2): A-frags for kt+1 loaded while kt's MFMAs run.
// Epilogue has NO FOUT guard: zero-padded weights/biases make padded
// outputs exactly 0 (value-identical, fewer cndmasks).
template<int KP, int MTILES, int NMT, int NWACT, int FOUT, bool TANH>
__device__ __forceinline__ void layer_mfma(
    const _Float16* __restrict__ whi, const _Float16* __restrict__ wlo,
    int wcoff, const float* __restrict__ biasP,
    _Float16* vhi, _Float16* vlo, _Float16* dhi, _Float16* ddh,
    int lane, int wv)
{
    constexpr int KT  = KP / 32;
    constexpr bool STG = (NMT <= 2);
    static_assert(MTILES == NMT * NWACT, "exact tiling expected");
    const int colS = lane & 15;
    const int kg   = lane >> 4;
    const bool act = (wv < NWACT);

    f4 accva[NMT], accvb[STG ? NMT : 1], accd[NMT], accdd[NMT];

    if (act) {
#pragma unroll
        for (int i = 0; i < NMT; ++i) {
            accva[i] = (f4){0.f, 0.f, 0.f, 0.f};
            accd[i]  = (f4){0.f, 0.f, 0.f, 0.f};
            accdd[i] = (f4){0.f, 0.f, 0.f, 0.f};
        }
        if constexpr (STG) {
#pragma unroll
            for (int i = 0; i < NMT; ++i)
                accvb[i] = (f4){0.f, 0.f, 0.f, 0.f};
        }

        const int boff = colS * STR + kg * 8;

        unsigned woff[NMT];
#pragma unroll
        for (int i = 0; i < NMT; ++i)
            woff[i] = (unsigned)(wcoff + ((wv + NWACT * i) * KT) * 512 + lane * 8);

        if constexpr (STG) {
            // ---- software-pipelined A-load path (full unroll: compiler
            //      renames buffers and deepens the pipeline) ----
            h8 Ah[NMT], Al[NMT], Ah2[NMT], Al2[NMT];
#pragma unroll
            for (int i = 0; i < NMT; ++i) {
                Ah[i] = *(const h8*)(whi + woff[i]);
                Al[i] = *(const h8*)(wlo + woff[i]);
            }
#pragma unroll
            for (int kt = 0; kt < KT; ++kt) {
                if (kt + 1 < KT) {
                    const int kwb = (kt + 1) * 512;
#pragma unroll
                    for (int i = 0; i < NMT; ++i) {
                        Ah2[i] = *(const h8*)(whi + woff[i] + kwb);
                        Al2[i] = *(const h8*)(wlo + woff[i] + kwb);
                    }
                }
                const int kb = kt * 32;
                h8 Bvh = *(const h8*)(vhi + boff + kb);
                h8 Bvl = *(const h8*)(vlo + boff + kb);
                h8 Bdh = *(const h8*)(dhi + boff + kb);
                h8 Bdd = *(const h8*)(ddh + boff + kb);
                __builtin_amdgcn_s_setprio(1);
#pragma unroll
                for (int i = 0; i < NMT; ++i) {
                    accva[i] = __builtin_amdgcn_mfma_f32_16x16x32_f16(Ah[i], Bvh, accva[i], 0, 0, 0);
                    accvb[i] = __builtin_amdgcn_mfma_f32_16x16x32_f16(Ah[i], Bvl, accvb[i], 0, 0, 0);
                    accvb[i] = __builtin_amdgcn_mfma_f32_16x16x32_f16(Al[i], Bvh, accvb[i], 0, 0, 0);
                    accd[i]  = __builtin_amdgcn_mfma_f32_16x16x32_f16(Ah[i], Bdh, accd[i],  0, 0, 0);
                    accdd[i] = __builtin_amdgcn_mfma_f32_16x16x32_f16(Ah[i], Bdd, accdd[i], 0, 0, 0);
                }
                __builtin_amdgcn_s_setprio(0);
                if (kt + 1 < KT) {
#pragma unroll
                    for (int i = 0; i < NMT; ++i) { Ah[i] = Ah2[i]; Al[i] = Al2[i]; }
                }
            }
        } else {
            // ---- inline-load path (L3: NMT=4, register-tight) ----
#pragma unroll
            for (int kt = 0; kt < KT; ++kt) {
                const int kb  = kt * 32;
                const int kwb = kt * 512;
                h8 Bvh = *(const h8*)(vhi + boff + kb);
                h8 Bvl = *(const h8*)(vlo + boff + kb);
                h8 Bdh = *(const h8*)(dhi + boff + kb);
                h8 Bdd = *(const h8*)(ddh + boff + kb);
                __builtin_amdgcn_s_setprio(1);
#pragma unroll
                for (int i = 0; i < NMT; ++i) {
                    h8 Ahi = *(const h8*)(whi + woff[i] + kwb);
                    h8 Alo = *(const h8*)(wlo + woff[i] + kwb);
                    accva[i] = __builtin_amdgcn_mfma_f32_16x16x32_f16(Ahi, Bvh, accva[i], 0, 0, 0);
                    accva[i] = __builtin_amdgcn_mfma_f32_16x16x32_f16(Ahi, Bvl, accva[i], 0, 0, 0);
                    accva[i] = __builtin_amdgcn_mfma_f32_16x16x32_f16(Alo, Bvh, accva[i], 0, 0, 0);
                    accd[i]  = __builtin_amdgcn_mfma_f32_16x16x32_f16(Ahi, Bdh, accd[i],  0, 0, 0);
                    accdd[i] = __builtin_amdgcn_mfma_f32_16x16x32_f16(Ahi, Bdd, accdd[i], 0, 0, 0);
                }
                __builtin_amdgcn_s_setprio(0);
            }
        }
    }
    __syncthreads();   // all reads of planes complete before in-place overwrite

    if (act) {
#pragma unroll
        for (int i = 0; i < NMT; ++i) {
            int mt = wv + NWACT * i;
            int o0 = mt * 16 + kg * 4;
            f4 bi = *(const f4*)(biasP + o0);
            h4 pvh, pvl, pdh, pdd;
#pragma unroll
            for (int r = 0; r < 4; ++r) {
                float zv;
                if constexpr (STG) zv = accva[i][r] + accvb[i][r] + bi[r];
                else               zv = accva[i][r] + bi[r];
                float zd  = accd[i][r];
                float zdd = accdd[i][r];
                float ov, od, odd;
                if constexpr (TANH) {
                    float t  = fast_tanh(zv);
                    float s2 = 1.0f - t * t;
                    ov  = t;
                    od  = s2 * zd;
                    odd = s2 * zdd - 2.0f * t * s2 * zd * zd;
                } else {
                    ov = zv; od = zd; odd = zdd;
                }
                // no FOUT guard: padded rows are exactly 0 by construction
                Split sv = split16(ov);
                pvh[r] = sv.hi; pvl[r] = sv.lo;
                pdh[r] = (_Float16)od;
                pdd[r] = (_Float16)odd;
            }
            int off = colS * STR + o0;
            *(h4*)(vhi + off) = pvh;
            *(h4*)(vlo + off) = pvl;
            *(h4*)(dhi + off) = pdh;
            *(h4*)(ddh + off) = pdd;
        }
    }
    __syncthreads();
}

// ---------------- main fused kernel ----------------
__global__ __launch_bounds__(THREADS, 4) void pinn_mfma(
    const float* __restrict__ W0, const float* __restrict__ b0,
    const float* __restrict__ x,
    const _Float16* __restrict__ whi, const float* __restrict__ biasP,
    float* __restrict__ out)
{
    __shared__ __align__(16) _Float16 smem[4 * BS * STR];   // 66,560 B
    __shared__ float xs[BS];
    __shared__ float cbv[BS];

    _Float16* vhi = smem + 0 * BS * STR;
    _Float16* vlo = smem + 1 * BS * STR;
    _Float16* dhi = smem + 2 * BS * STR;
    _Float16* ddh = smem + 3 * BS * STR;

    const int tid  = threadIdx.x;
    const int bid  = blockIdx.x;
    const int lane = tid & 63;
    const int wv   = tid >> 6;
    const _Float16* wlo = whi + SW;

    if (tid < BS) xs[tid] = x[bid * BS + tid];
    __syncthreads();

    // ---- layer 0: 1 -> 20, write padded-K (32) input planes ----
    {
        int s = tid >> 5;       // 0..15
        int k = tid & 31;       // 0..31
        float v0 = 0.f, v1 = 0.f, v2 = 0.f;
        if (k < 20) {
            float w  = W0[k];
            float z  = w * xs[s] + b0[k];
            float t  = fast_tanh(z);
            float s2 = 1.0f - t * t;
            v0 = t; v1 = s2 * w; v2 = -2.0f * t * s2 * w * w;
        }
        Split s0 = split16(v0);
        int off = s * STR + k;
        vhi[off] = s0.hi;           vlo[off] = s0.lo;
        dhi[off] = (_Float16)v1;    ddh[off] = (_Float16)v2;
    }
    __syncthreads();

    //          KP   MT NMT NWA FOUT
    layer_mfma< 32,  4, 1,  4,  50, true>(whi, wlo, C1, biasP + BP1, vhi, vlo, dhi, ddh, lane, wv);
    layer_mfma< 64, 14, 2,  7, 200, true>(whi, wlo, C2, biasP + BP2, vhi, vlo, dhi, ddh, lane, wv);
    layer_mfma<224, 32, 4,  8, 500, true>(whi, wlo, C3, biasP + BP3, vhi, vlo, dhi, ddh, lane, wv);
    layer_mfma<512, 14, 2,  7, 200, true>(whi, wlo, C4, biasP + BP4, vhi, vlo, dhi, ddh, lane, wv);

    // ---- layer 5: 200 -> 100 linear -> U, Uxx, F; then tail via MFMA ----
    {
        constexpr int KT = 7;
        const int colS = lane & 15;
        const int kg   = lane >> 4;
        const bool act = (wv < 7);
        float* Umf = (float*)dhi;          // 16 x 104 f32 in dead dhi plane
        f4 ava = (f4){0.f,0.f,0.f,0.f}, avb = ava, ad = ava, add = ava;
        if (act) {
            const int boff = colS * STR + kg * 8;
            const unsigned w5off = (unsigned)(C5 + (wv * KT) * 512 + lane * 8);
            h8 Ah = *(const h8*)(whi + w5off);
            h8 Al = *(const h8*)(wlo + w5off);
            h8 Ah2, Al2;
#pragma unroll
            for (int kt = 0; kt < KT; ++kt) {
                if (kt + 1 < KT) {
                    const int kwb = (kt + 1) * 512;
                    Ah2 = *(const h8*)(whi + w5off + kwb);
                    Al2 = *(const h8*)(wlo + w5off + kwb);
                }
                const int kb = kt * 32;
                h8 Bvh = *(const h8*)(vhi + boff + kb);
                h8 Bvl = *(const h8*)(vlo + boff + kb);
                h8 Bdh = *(const h8*)(dhi + boff + kb);
                h8 Bdd = *(const h8*)(ddh + boff + kb);
                __builtin_amdgcn_s_setprio(1);
                ava = __builtin_amdgcn_mfma_f32_16x16x32_f16(Ah, Bvh, ava, 0, 0, 0);
                avb = __builtin_amdgcn_mfma_f32_16x16x32_f16(Ah, Bvl, avb, 0, 0, 0);
                avb = __builtin_amdgcn_mfma_f32_16x16x32_f16(Al, Bvh, avb, 0, 0, 0);
                ad  = __builtin_amdgcn_mfma_f32_16x16x32_f16(Ah, Bdh, ad,  0, 0, 0);
                add = __builtin_amdgcn_mfma_f32_16x16x32_f16(Ah, Bdd, add, 0, 0, 0);
                __builtin_amdgcn_s_setprio(0);
                if (kt + 1 < KT) { Ah = Ah2; Al = Al2; }
            }
        }
        __syncthreads();   // all plane reads done; vhi/vlo reused for split-F,
                           // dhi reused for fp32 U. (ddh unused.)

        // epilogue: U, Uxx, F; write F split into vhi/vlo (B-layout [s][k]),
        // U fp32 into Umf.  (Guards kept here: Fm/Um row stride is 104.)
        if (act) {
            int o0 = wv * 16 + kg * 4;
            if (o0 < Q) {                      // o0 multiple of 4; o0<100 => o0+3<=99
                f4 bi = *(const f4*)(biasP + BP5 + o0);
                float xv = xs[colS];
                float xm = xv * xv - 1.0f;
                f4 uo; h4 fh, fl;
#pragma unroll
                for (int r = 0; r < 4; ++r) {
                    float gv  = ava[r] + avb[r] + bi[r];
                    float gd  = ad[r];
                    float gdd = add[r];
                    float U   = -1.0f + xm * gv;
                    float Uxx = 2.0f * gv + 4.0f * xv * gd + xm * gdd;
                    float Fv  = 5.0f * U * U * U - 5.0f * U - 0.0005f * Uxx;
                    uo[r] = U;
                    Split sf = split16(Fv);
                    fh[r] = sf.hi; fl[r] = sf.lo;
                }
                *(f4*)(Umf + colS * 104 + o0)  = uo;
                *(h4*)(vhi + colS * STR + o0) = fh;
                *(h4*)(vlo + colS * STR + o0) = fl;
            }
        }
        // zero-pad k in [100,128) of the F planes (16 rows x 28 halves x 2)
        if (tid < 224) {
            int pl  = tid / 112;
            int u   = tid - pl * 112;
            int row = u / 7, c = u - row * 7;
            _Float16* P = pl ? vlo : vhi;
            *(h4*)(P + row * STR + 100 + c * 4) = (h4){0,0,0,0};
        }
        __syncthreads();

        // ---- tail MFMA: [U0;cb] rows = Aext(112x100) @ F, 3-product split ----
        f4 tva = (f4){0.f,0.f,0.f,0.f}, tvb = tva;
        if (act) {
            const int boff = colS * STR + kg * 8;
            const unsigned aoff = (unsigned)(C6 + (wv * 4) * 512 + lane * 8);
            h8 Ah = *(const h8*)(whi + aoff);
            h8 Al = *(const h8*)(wlo + aoff);
            h8 Ah2, Al2;
#pragma unroll
            for (int kt = 0; kt < 4; ++kt) {
                if (kt < 3) {
                    Ah2 = *(const h8*)(whi + aoff + (kt + 1) * 512);
                    Al2 = *(const h8*)(wlo + aoff + (kt + 1) * 512);
                }
                h8 Bh = *(const h8*)(vhi + boff + kt * 32);
                h8 Bl = *(const h8*)(vlo + boff + kt * 32);
                __builtin_amdgcn_s_setprio(1);
                tva = __builtin_amdgcn_mfma_f32_16x16x32_f16(Ah, Bh, tva, 0, 0, 0);
                tvb = __builtin_amdgcn_mfma_f32_16x16x32_f16(Ah, Bl, tvb, 0, 0, 0);
                tvb = __builtin_amdgcn_mfma_f32_16x16x32_f16(Al, Bh, tvb, 0, 0, 0);
                __builtin_amdgcn_s_setprio(0);
                if (kt < 3) { Ah = Ah2; Al = Al2; }
            }
        }
        // row 100 (= F@bvec^T) lives at wv==6, kg==1, r==0; broadcast per sample
        if (wv == 6 && kg == 1) cbv[colS] = DTC * (tva[0] + tvb[0]);
        __syncthreads();

        // ---- final combine + store ----
        if (act) {
            int o0 = wv * 16 + kg * 4;
            if (o0 < Q) {
                float cbs = cbv[colS];
                f4 um = *(const f4*)(Umf + colS * 104 + o0);
                f4 u0, u1;
#pragma unroll
                for (int r = 0; r < 4; ++r) {
                    u0[r] = um[r] + DTC * (tva[r] + tvb[r]);
                    u1[r] = u0[r] - cbs;
                }
                int sg = bid * BS + colS;
                *(f4*)(out + sg * Q + o0) = u0;
                *(f4*)(out + NSAMP * Q + sg * Q + o0) = u1;
            }
        }
    }
}

extern "C" void kernel_launch(void* const* d_in, const int* in_sizes, int n_in,
                              void* d_out, int out_size, void* d_ws, size_t ws_size,
                              hipStream_t stream) {
    const float* W0 = (const float*)d_in[0];
    const float* b0 = (const float*)d_in[1];
    const float* W1 = (const float*)d_in[2];
    const float* b1 = (const float*)d_in[3];
    const float* W2 = (const float*)d_in[4];
    const float* b2 = (const float*)d_in[5];
    const float* W3 = (const float*)d_in[6];
    const float* b3 = (const float*)d_in[7];
    const float* W4 = (const float*)d_in[8];
    const float* b4 = (const float*)d_in[9];
    const float* W5 = (const float*)d_in[10];
    const float* b5 = (const float*)d_in[11];
    const float* x  = (const float*)d_in[12];
    const float* A  = (const float*)d_in[13];
    const float* bv = (const float*)d_in[14];
    float* out = (float*)d_out;

    _Float16* whi = (_Float16*)d_ws;
    float* biasP  = (float*)((char*)d_ws + WS_BIAS_BYTE_OFF);

    prepass<<<(SW + BPTOT + 255) / 256, 256, 0, stream>>>(
        W1, b1, W2, b2, W3, b3, W4, b4, W5, b5, A, bv, whi, biasP);

    pinn_mfma<<<NSAMP / BS, THREADS, 0, stream>>>(
        W0, b0, x, whi, biasP, out);
}

// Round 11
// 304.470 us; speedup vs baseline: 1.2832x; 1.0012x over previous
//
#include <hip/hip_runtime.h>
#include <hip/hip_bf16.h>

// PINN fused forward+jvp^2 via split-fp16 MFMA.
// R20 = R19 (234us: BS=16, 512thr, 2 blocks/CU, 16x16x32 split-fp16,
// staged A, vb-split, setprio, MFMA tail, no dead guards, full unroll)
// + EPILOGUE HOIST: in STG layers (L1/L2/L4) and L5, the epilogue VALU
// (tanh, derivatives, split16) is computed into registers BEFORE the
// first barrier -- it depends only on the wave's own accumulators. Only
// the tiny plane-WRITE block stays between the barriers (~50cy vs
// ~700cy). The VALU bulk now overlaps other waves'/block's MFMA phase
// instead of serializing the whole CU. L3 keeps the old post-barrier
// epilogue (hoist there = +32 VGPR > 128 unified budget at 48 AGPR).

#define NSAMP 65536
#define Q     100
#define DTC   0.8f
#define BS    16
#define THREADS 512
#define STR   520          // LDS plane stride (halves); MUST be mult of 8

typedef _Float16 h8 __attribute__((ext_vector_type(8)));
typedef _Float16 h4 __attribute__((ext_vector_type(4)));
typedef float    f4 __attribute__((ext_vector_type(4)));

// ---- packed fragment-ready weight geometry (halves) ----
// per layer: MT * KT * 512 halves (frag = 64 lanes x 8 halves)
// L1: MT=4,  KT=1  ->   2048
// L2: MT=14, KT=2  ->  14336
// L3: MT=32, KT=7  -> 114688
// L4: MT=14, KT=16 -> 114688
// L5: MT=7,  KT=7  ->  25088
// L6 (Aext=[A;bvec;0], 112x100): MT=7, KT=4 -> 14336
#define SW 285184
#define C1 0
#define C2 2048
#define C3 16384
#define C4 131072
#define C5 245760
#define C6 270848
#define BP1 0
#define BP2 64
#define BP3 288
#define BP4 800
#define BP5 1024
#define BPTOT 1136
#define WS_BIAS_BYTE_OFF (SW*2*2)

__device__ __forceinline__ float fast_tanh(float z) {
    float az = fabsf(z);
    float e  = __expf(-2.0f * az);
    float r  = __builtin_amdgcn_rcpf(1.0f + e);
    float t  = (1.0f - e) * r;
    return copysignf(t, z);
}

struct Split { _Float16 hi, lo; };
__device__ __forceinline__ Split split16(float v) {
    Split s;
    s.hi = (_Float16)v;
    s.lo = (_Float16)(v - (float)s.hi);
    return s;
}

// ---------------- pre-pass: split/pad/PACK weights + biases + Aext into d_ws ----------------
__global__ __launch_bounds__(256) void prepass(
    const float* __restrict__ W1, const float* __restrict__ b1,
    const float* __restrict__ W2, const float* __restrict__ b2,
    const float* __restrict__ W3, const float* __restrict__ b3,
    const float* __restrict__ W4, const float* __restrict__ b4,
    const float* __restrict__ W5, const float* __restrict__ b5,
    const float* __restrict__ Amat, const float* __restrict__ bvec,
    _Float16* __restrict__ whi, float* __restrict__ biasP)
{
    int idx = blockIdx.x * 256 + threadIdx.x;
    _Float16* wlo = whi + SW;
    if (idx < SW) {
        int base, KT, K, FOUT; const float* W; bool ext = false;
        if      (idx < C2) { base=C1; KT=1;  K=20;  FOUT=50;  W=W1; }
        else if (idx < C3) { base=C2; KT=2;  K=50;  FOUT=200; W=W2; }
        else if (idx < C4) { base=C3; KT=7;  K=200; FOUT=500; W=W3; }
        else if (idx < C5) { base=C4; KT=16; K=500; FOUT=200; W=W4; }
        else if (idx < C6) { base=C5; KT=7;  K=200; FOUT=100; W=W5; }
        else               { base=C6; KT=4;  K=100; FOUT=101; W=Amat; ext = true; }
        int r    = idx - base;
        int frag = r >> 9;
        int f    = r & 511;
        int lane = f >> 3;
        int e    = f & 7;
        int colS = lane & 15;
        int kg   = lane >> 4;
        int mt   = frag / KT;
        int kt   = frag - mt * KT;
        int o = mt * 16 + colS;
        int k = kt * 32 + kg * 8 + e;
        float v = 0.f;
        if (o < FOUT && k < K) {
            if (ext && o == 100) v = bvec[k];
            else                 v = W[o * K + k];
        }
        Split sp = split16(v);
        whi[idx] = sp.hi; wlo[idx] = sp.lo;
    } else if (idx < SW + BPTOT) {
        int b = idx - SW;
        const float* src; int FOUT; int o;
        if      (b < BP2)  { src=b1; FOUT=50;  o=b;        }
        else if (b < BP3)  { src=b2; FOUT=200; o=b-BP2;    }
        else if (b < BP4)  { src=b3; FOUT=500; o=b-BP3;    }
        else if (b < BP5)  { src=b4; FOUT=200; o=b-BP4;    }
        else               { src=b5; FOUT=100; o=b-BP5;    }
        biasP[b] = (o < FOUT) ? src[o] : 0.f;
    }
}

// ---------------- one MFMA layer ----------------
// Planes (LDS, stride STR halves): vhi, vlo (split v-state), dhi, ddh (fp16 d/dd).
// B-frag: lane l -> col = l&15 (sample), k0 = (l>>4)*8 + kt*32.
// A-frag: PACKED: base + (mt*KT + kt)*512 + lane*8  -> coalesced 1KB load.
// C/D: col(lane&15)=sample, row((lane>>4)*4+reg)=output neuron.
// STG path (NMT<=2): A-frags staged 1-ahead; epilogue VALU HOISTED before
// barrier 1 (results in regs), only plane writes between barriers.
// Inline path (L3): old structure (register-tight).
template<int KP, int MTILES, int NMT, int NWACT, int FOUT, bool TANH>
__device__ __forceinline__ void layer_mfma(
    const _Float16* __restrict__ whi, const _Float16* __restrict__ wlo,
    int wcoff, const float* __restrict__ biasP,
    _Float16* vhi, _Float16* vlo, _Float16* dhi, _Float16* ddh,
    int lane, int wv)
{
    constexpr int KT  = KP / 32;
    constexpr bool STG = (NMT <= 2);
    static_assert(MTILES == NMT * NWACT, "exact tiling expected");
    const int colS = lane & 15;
    const int kg   = lane >> 4;
    const bool act = (wv < NWACT);

    f4 accva[NMT], accvb[STG ? NMT : 1], accd[NMT], accdd[NMT];

    if constexpr (STG) {
        h4 pvh[NMT], pvl[NMT], pdh[NMT], pdd[NMT];   // hoisted results
        if (act) {
#pragma unroll
            for (int i = 0; i < NMT; ++i) {
                accva[i] = (f4){0.f, 0.f, 0.f, 0.f};
                accvb[i] = (f4){0.f, 0.f, 0.f, 0.f};
                accd[i]  = (f4){0.f, 0.f, 0.f, 0.f};
                accdd[i] = (f4){0.f, 0.f, 0.f, 0.f};
            }
            const int boff = colS * STR + kg * 8;
            unsigned woff[NMT];
#pragma unroll
            for (int i = 0; i < NMT; ++i)
                woff[i] = (unsigned)(wcoff + ((wv + NWACT * i) * KT) * 512 + lane * 8);

            h8 Ah[NMT], Al[NMT], Ah2[NMT], Al2[NMT];
#pragma unroll
            for (int i = 0; i < NMT; ++i) {
                Ah[i] = *(const h8*)(whi + woff[i]);
                Al[i] = *(const h8*)(wlo + woff[i]);
            }
#pragma unroll
            for (int kt = 0; kt < KT; ++kt) {
                if (kt + 1 < KT) {
                    const int kwb = (kt + 1) * 512;
#pragma unroll
                    for (int i = 0; i < NMT; ++i) {
                        Ah2[i] = *(const h8*)(whi + woff[i] + kwb);
                        Al2[i] = *(const h8*)(wlo + woff[i] + kwb);
                    }
                }
                const int kb = kt * 32;
                h8 Bvh = *(const h8*)(vhi + boff + kb);
                h8 Bvl = *(const h8*)(vlo + boff + kb);
                h8 Bdh = *(const h8*)(dhi + boff + kb);
                h8 Bdd = *(const h8*)(ddh + boff + kb);
                __builtin_amdgcn_s_setprio(1);
#pragma unroll
                for (int i = 0; i < NMT; ++i) {
                    accva[i] = __builtin_amdgcn_mfma_f32_16x16x32_f16(Ah[i], Bvh, accva[i], 0, 0, 0);
                    accvb[i] = __builtin_amdgcn_mfma_f32_16x16x32_f16(Ah[i], Bvl, accvb[i], 0, 0, 0);
                    accvb[i] = __builtin_amdgcn_mfma_f32_16x16x32_f16(Al[i], Bvh, accvb[i], 0, 0, 0);
                    accd[i]  = __builtin_amdgcn_mfma_f32_16x16x32_f16(Ah[i], Bdh, accd[i],  0, 0, 0);
                    accdd[i] = __builtin_amdgcn_mfma_f32_16x16x32_f16(Ah[i], Bdd, accdd[i], 0, 0, 0);
                }
                __builtin_amdgcn_s_setprio(0);
                if (kt + 1 < KT) {
#pragma unroll
                    for (int i = 0; i < NMT; ++i) { Ah[i] = Ah2[i]; Al[i] = Al2[i]; }
                }
            }

            // ---- hoisted epilogue compute (pre-barrier, regs only) ----
#pragma unroll
            for (int i = 0; i < NMT; ++i) {
                int mt = wv + NWACT * i;
                int o0 = mt * 16 + kg * 4;
                f4 bi = *(const f4*)(biasP + o0);
#pragma unroll
                for (int r = 0; r < 4; ++r) {
                    float zv  = accva[i][r] + accvb[i][r] + bi[r];
                    float zd  = accd[i][r];
                    float zdd = accdd[i][r];
                    float ov, od, odd;
                    if constexpr (TANH) {
                        float t  = fast_tanh(zv);
                        float s2 = 1.0f - t * t;
                        ov  = t;
                        od  = s2 * zd;
                        odd = s2 * zdd - 2.0f * t * s2 * zd * zd;
                    } else {
                        ov = zv; od = zd; odd = zdd;
                    }
                    Split sv = split16(ov);
                    pvh[i][r] = sv.hi; pvl[i][r] = sv.lo;
                    pdh[i][r] = (_Float16)od;
                    pdd[i][r] = (_Float16)odd;
                }
            }
        }
        __syncthreads();   // all reads of planes complete before overwrite
        if (act) {
#pragma unroll
            for (int i = 0; i < NMT; ++i) {
                int mt = wv + NWACT * i;
                int off = colS * STR + mt * 16 + kg * 4;
                *(h4*)(vhi + off) = pvh[i];
                *(h4*)(vlo + off) = pvl[i];
                *(h4*)(dhi + off) = pdh[i];
                *(h4*)(ddh + off) = pdd[i];
            }
        }
        __syncthreads();
    } else {
        // ---- inline-load path (L3: NMT=4, register-tight, old structure) ----
        if (act) {
#pragma unroll
            for (int i = 0; i < NMT; ++i) {
                accva[i] = (f4){0.f, 0.f, 0.f, 0.f};
                accd[i]  = (f4){0.f, 0.f, 0.f, 0.f};
                accdd[i] = (f4){0.f, 0.f, 0.f, 0.f};
            }
            const int boff = colS * STR + kg * 8;
            unsigned woff[NMT];
#pragma unroll
            for (int i = 0; i < NMT; ++i)
                woff[i] = (unsigned)(wcoff + ((wv + NWACT * i) * KT) * 512 + lane * 8);
#pragma unroll
            for (int kt = 0; kt < KT; ++kt) {
                const int kb  = kt * 32;
                const int kwb = kt * 512;
                h8 Bvh = *(const h8*)(vhi + boff + kb);
                h8 Bvl = *(const h8*)(vlo + boff + kb);
                h8 Bdh = *(const h8*)(dhi + boff + kb);
                h8 Bdd = *(const h8*)(ddh + boff + kb);
                __builtin_amdgcn_s_setprio(1);
#pragma unroll
                for (int i = 0; i < NMT; ++i) {
                    h8 Ahi = *(const h8*)(whi + woff[i] + kwb);
                    h8 Alo = *(const h8*)(wlo + woff[i] + kwb);
                    accva[i] = __builtin_amdgcn_mfma_f32_16x16x32_f16(Ahi, Bvh, accva[i], 0, 0, 0);
                    accva[i] = __builtin_amdgcn_mfma_f32_16x16x32_f16(Ahi, Bvl, accva[i], 0, 0, 0);
                    accva[i] = __builtin_amdgcn_mfma_f32_16x16x32_f16(Alo, Bvh, accva[i], 0, 0, 0);
                    accd[i]  = __builtin_amdgcn_mfma_f32_16x16x32_f16(Ahi, Bdh, accd[i],  0, 0, 0);
                    accdd[i] = __builtin_amdgcn_mfma_f32_16x16x32_f16(Ahi, Bdd, accdd[i], 0, 0, 0);
                }
                __builtin_amdgcn_s_setprio(0);
            }
        }
        __syncthreads();
        if (act) {
#pragma unroll
            for (int i = 0; i < NMT; ++i) {
                int mt = wv + NWACT * i;
                int o0 = mt * 16 + kg * 4;
                f4 bi = *(const f4*)(biasP + o0);
                h4 pvh, pvl, pdh, pdd;
#pragma unroll
                for (int r = 0; r < 4; ++r) {
                    float zv  = accva[i][r] + bi[r];
                    float zd  = accd[i][r];
                    float zdd = accdd[i][r];
                    float ov, od, odd;
                    if constexpr (TANH) {
                        float t  = fast_tanh(zv);
                        float s2 = 1.0f - t * t;
                        ov  = t;
                        od  = s2 * zd;
                        odd = s2 * zdd - 2.0f * t * s2 * zd * zd;
                    } else {
                        ov = zv; od = zd; odd = zdd;
                    }
                    Split sv = split16(ov);
                    pvh[r] = sv.hi; pvl[r] = sv.lo;
                    pdh[r] = (_Float16)od;
                    pdd[r] = (_Float16)odd;
                }
                int off = colS * STR + o0;
                *(h4*)(vhi + off) = pvh;
                *(h4*)(vlo + off) = pvl;
                *(h4*)(dhi + off) = pdh;
                *(h4*)(ddh + off) = pdd;
            }
        }
        __syncthreads();
    }
}

// ---------------- main fused kernel ----------------
__global__ __launch_bounds__(THREADS, 4) void pinn_mfma(
    const float* __restrict__ W0, const float* __restrict__ b0,
    const float* __restrict__ x,
    const _Float16* __restrict__ whi, const float* __restrict__ biasP,
    float* __restrict__ out)
{
    __shared__ __align__(16) _Float16 smem[4 * BS * STR];   // 66,560 B
    __shared__ float xs[BS];
    __shared__ float cbv[BS];

    _Float16* vhi = smem + 0 * BS * STR;
    _Float16* vlo = smem + 1 * BS * STR;
    _Float16* dhi = smem + 2 * BS * STR;
    _Float16* ddh = smem + 3 * BS * STR;

    const int tid  = threadIdx.x;
    const int bid  = blockIdx.x;
    const int lane = tid & 63;
    const int wv   = tid >> 6;
    const _Float16* wlo = whi + SW;

    if (tid < BS) xs[tid] = x[bid * BS + tid];
    __syncthreads();

    // ---- layer 0: 1 -> 20, write padded-K (32) input planes ----
    {
        int s = tid >> 5;       // 0..15
        int k = tid & 31;       // 0..31
        float v0 = 0.f, v1 = 0.f, v2 = 0.f;
        if (k < 20) {
            float w  = W0[k];
            float z  = w * xs[s] + b0[k];
            float t  = fast_tanh(z);
            float s2 = 1.0f - t * t;
            v0 = t; v1 = s2 * w; v2 = -2.0f * t * s2 * w * w;
        }
        Split s0 = split16(v0);
        int off = s * STR + k;
        vhi[off] = s0.hi;           vlo[off] = s0.lo;
        dhi[off] = (_Float16)v1;    ddh[off] = (_Float16)v2;
    }
    __syncthreads();

    //          KP   MT NMT NWA FOUT
    layer_mfma< 32,  4, 1,  4,  50, true>(whi, wlo, C1, biasP + BP1, vhi, vlo, dhi, ddh, lane, wv);
    layer_mfma< 64, 14, 2,  7, 200, true>(whi, wlo, C2, biasP + BP2, vhi, vlo, dhi, ddh, lane, wv);
    layer_mfma<224, 32, 4,  8, 500, true>(whi, wlo, C3, biasP + BP3, vhi, vlo, dhi, ddh, lane, wv);
    layer_mfma<512, 14, 2,  7, 200, true>(whi, wlo, C4, biasP + BP4, vhi, vlo, dhi, ddh, lane, wv);

    // ---- layer 5: 200 -> 100 linear -> U, Uxx, F; then tail via MFMA ----
    {
        constexpr int KT = 7;
        const int colS = lane & 15;
        const int kg   = lane >> 4;
        const bool act = (wv < 7);
        float* Umf = (float*)dhi;          // 16 x 104 f32 in dead dhi plane
        f4 uo; h4 fh, fl;                  // hoisted L5 epilogue results
        const int o0L5 = wv * 16 + kg * 4;
        if (act) {
            f4 ava = (f4){0.f,0.f,0.f,0.f}, avb = ava, ad = ava, add = ava;
            const int boff = colS * STR + kg * 8;
            const unsigned w5off = (unsigned)(C5 + (wv * KT) * 512 + lane * 8);
            h8 Ah = *(const h8*)(whi + w5off);
            h8 Al = *(const h8*)(wlo + w5off);
            h8 Ah2, Al2;
#pragma unroll
            for (int kt = 0; kt < KT; ++kt) {
                if (kt + 1 < KT) {
                    const int kwb = (kt + 1) * 512;
                    Ah2 = *(const h8*)(whi + w5off + kwb);
                    Al2 = *(const h8*)(wlo + w5off + kwb);
                }
                const int kb = kt * 32;
                h8 Bvh = *(const h8*)(vhi + boff + kb);
                h8 Bvl = *(const h8*)(vlo + boff + kb);
                h8 Bdh = *(const h8*)(dhi + boff + kb);
                h8 Bdd = *(const h8*)(ddh + boff + kb);
                __builtin_amdgcn_s_setprio(1);
                ava = __builtin_amdgcn_mfma_f32_16x16x32_f16(Ah, Bvh, ava, 0, 0, 0);
                avb = __builtin_amdgcn_mfma_f32_16x16x32_f16(Ah, Bvl, avb, 0, 0, 0);
                avb = __builtin_amdgcn_mfma_f32_16x16x32_f16(Al, Bvh, avb, 0, 0, 0);
                ad  = __builtin_amdgcn_mfma_f32_16x16x32_f16(Ah, Bdh, ad,  0, 0, 0);
                add = __builtin_amdgcn_mfma_f32_16x16x32_f16(Ah, Bdd, add, 0, 0, 0);
                __builtin_amdgcn_s_setprio(0);
                if (kt + 1 < KT) { Ah = Ah2; Al = Al2; }
            }
            // hoisted epilogue compute (pre-barrier): U, F split
            if (o0L5 < Q) {
                f4 bi = *(const f4*)(biasP + BP5 + o0L5);
                float xv = xs[colS];
                float xm = xv * xv - 1.0f;
#pragma unroll
                for (int r = 0; r < 4; ++r) {
                    float gv  = ava[r] + avb[r] + bi[r];
                    float gd  = ad[r];
                    float gdd = add[r];
                    float U   = -1.0f + xm * gv;
                    float Uxx = 2.0f * gv + 4.0f * xv * gd + xm * gdd;
                    float Fv  = 5.0f * U * U * U - 5.0f * U - 0.0005f * Uxx;
                    uo[r] = U;
                    Split sf = split16(Fv);
                    fh[r] = sf.hi; fl[r] = sf.lo;
                }
            }
        }
        __syncthreads();   // all plane reads done; vhi/vlo reused for split-F,
                           // dhi reused for fp32 U. (ddh unused.)

        if (act && o0L5 < Q) {
            *(f4*)(Umf + colS * 104 + o0L5)  = uo;
            *(h4*)(vhi + colS * STR + o0L5) = fh;
            *(h4*)(vlo + colS * STR + o0L5) = fl;
        }
        // zero-pad k in [100,128) of the F planes (16 rows x 28 halves x 2)
        if (tid < 224) {
            int pl  = tid / 112;
            int u   = tid - pl * 112;
            int row = u / 7, c = u - row * 7;
            _Float16* P = pl ? vlo : vhi;
            *(h4*)(P + row * STR + 100 + c * 4) = (h4){0,0,0,0};
        }
        __syncthreads();

        // ---- tail MFMA: [U0;cb] rows = Aext(112x100) @ F, 3-product split ----
        f4 tva = (f4){0.f,0.f,0.f,0.f}, tvb = tva;
        if (act) {
            const int boff = colS * STR + kg * 8;
            const unsigned aoff = (unsigned)(C6 + (wv * 4) * 512 + lane * 8);
            h8 Ah = *(const h8*)(whi + aoff);
            h8 Al = *(const h8*)(wlo + aoff);
            h8 Ah2, Al2;
#pragma unroll
            for (int kt = 0; kt < 4; ++kt) {
                if (kt < 3) {
                    Ah2 = *(const h8*)(whi + aoff + (kt + 1) * 512);
                    Al2 = *(const h8*)(wlo + aoff + (kt + 1) * 512);
                }
                h8 Bh = *(const h8*)(vhi + boff + kt * 32);
                h8 Bl = *(const h8*)(vlo + boff + kt * 32);
                __builtin_amdgcn_s_setprio(1);
                tva = __builtin_amdgcn_mfma_f32_16x16x32_f16(Ah, Bh, tva, 0, 0, 0);
                tvb = __builtin_amdgcn_mfma_f32_16x16x32_f16(Ah, Bl, tvb, 0, 0, 0);
                tvb = __builtin_amdgcn_mfma_f32_16x16x32_f16(Al, Bh, tvb, 0, 0, 0);
                __builtin_amdgcn_s_setprio(0);
                if (kt < 3) { Ah = Ah2; Al = Al2; }
            }
        }
        // row 100 (= F@bvec^T) lives at wv==6, kg==1, r==0; broadcast per sample
        if (wv == 6 && kg == 1) cbv[colS] = DTC * (tva[0] + tvb[0]);
        __syncthreads();

        // ---- final combine + store ----
        if (act && o0L5 < Q) {
            float cbs = cbv[colS];
            f4 um = *(const f4*)(Umf + colS * 104 + o0L5);
            f4 u0, u1;
#pragma unroll
            for (int r = 0; r < 4; ++r) {
                u0[r] = um[r] + DTC * (tva[r] + tvb[r]);
                u1[r] = u0[r] - cbs;
            }
            int sg = bid * BS + colS;
            *(f4*)(out + sg * Q + o0L5) = u0;
            *(f4*)(out + NSAMP * Q + sg * Q + o0L5) = u1;
        }
    }
}

extern "C" void kernel_launch(void* const* d_in, const int* in_sizes, int n_in,
                              void* d_out, int out_size, void* d_ws, size_t ws_size,
                              hipStream_t stream) {
    const float* W0 = (const float*)d_in[0];
    const float* b0 = (const float*)d_in[1];
    const float* W1 = (const float*)d_in[2];
    const float* b1 = (const float*)d_in[3];
    const float* W2 = (const float*)d_in[4];
    const float* b2 = (const float*)d_in[5];
    const float* W3 = (const float*)d_in[6];
    const float* b3 = (const float*)d_in[7];
    const float* W4 = (const float*)d_in[8];
    const float* b4 = (const float*)d_in[9];
    const float* W5 = (const float*)d_in[10];
    const float* b5 = (const float*)d_in[11];
    const float* x  = (const float*)d_in[12];
    const float* A  = (const float*)d_in[13];
    const float* bv = (const float*)d_in[14];
    float* out = (float*)d_out;

    _Float16* whi = (_Float16*)d_ws;
    float* biasP  = (float*)((char*)d_ws + WS_BIAS_BYTE_OFF);

    prepass<<<(SW + BPTOT + 255) / 256, 256, 0, stream>>>(
        W1, b1, W2, b2, W3, b3, W4, b4, W5, b5, A, bv, whi, biasP);

    pinn_mfma<<<NSAMP / BS, THREADS, 0, stream>>>(
        W0, b0, x, whi, biasP, out);
}